// Round 4
// baseline (48.973 us; speedup 1.0000x reference)
//
#include <hip/hip_runtime.h>
#include <hip/hip_bf16.h>

// Problem constants (from reference): B=8, C=16, H=512, W=512, M=15, N=15
#define BC    128          // B*C
#define Hh    512
#define Ww    512
#define P16   16           // M+1
#define Q16   16           // N+1
#define HTILE 32           // h rows per eval block
#define NHT   (Hh / HTILE) // 16 h-tiles

typedef float f32x4 __attribute__((ext_vector_type(4)));  // native vec for nontemporal store

// ---------------------------------------------------------------------------
// Kernel 1: extract separable factors from the provided basis input.
// basis[n, p, q] = Bu[h,p] * Bv[w,q] with n = h*W + w; Bernstein rows sum to 1.
//   Bu[h,p] = sum_q basis[h*W + 0, p, q]
//   Bv[w,q] = sum_p basis[0*W + w, p, q]
// ---------------------------------------------------------------------------
__global__ void extract_factors(const float* __restrict__ basis,
                                float* __restrict__ Bu,
                                float* __restrict__ Bv) {
    int t = blockIdx.x * blockDim.x + threadIdx.x;   // 0..1023
    if (t < Hh) {
        const float* row = basis + (size_t)t * Ww * (P16 * Q16);
        #pragma unroll
        for (int p = 0; p < P16; ++p) {
            float s = 0.f;
            #pragma unroll
            for (int q = 0; q < Q16; ++q) s += row[p * Q16 + q];
            Bu[t * P16 + p] = s;
        }
    } else if (t < Hh + Ww) {
        int w = t - Hh;
        const float* row = basis + (size_t)w * (P16 * Q16);
        #pragma unroll
        for (int q = 0; q < Q16; ++q) {
            float s = 0.f;
            #pragma unroll
            for (int p = 0; p < P16; ++p) s += row[p * Q16 + q];
            Bv[w * Q16 + q] = s;
        }
    }
}

// ---------------------------------------------------------------------------
// Kernel 2: T[bc, p, w] = sum_q K[bc, p, q] * Bv[w, q]    (4 MB to workspace)
// One block per bc; thread t owns w = 2t, 2t+1.
// ---------------------------------------------------------------------------
__global__ __launch_bounds__(256)
void build_T(const float* __restrict__ K,
             const float* __restrict__ Bv,
             float* __restrict__ T) {
    __shared__ float K_s[P16 * Q16];
    const int bc = blockIdx.x;
    const int t  = threadIdx.x;

    K_s[t] = K[(size_t)bc * (P16 * Q16) + t];
    __syncthreads();

    const int w0 = t * 2;
    const float* bvp = Bv + (size_t)w0 * Q16;   // 128 B contiguous per thread
    float bv0[Q16], bv1[Q16];
    #pragma unroll
    for (int q = 0; q < Q16; ++q) { bv0[q] = bvp[q]; bv1[q] = bvp[Q16 + q]; }

    float* Tp = T + (size_t)bc * (P16 * Ww);
    #pragma unroll
    for (int p = 0; p < P16; ++p) {
        float s0 = 0.f, s1 = 0.f;
        #pragma unroll
        for (int q = 0; q < Q16; ++q) {
            float k = K_s[p * Q16 + q];          // wave-uniform broadcast
            s0 = fmaf(k, bv0[q], s0);
            s1 = fmaf(k, bv1[q], s1);
        }
        *(float2*)&Tp[p * Ww + w0] = make_float2(s0, s1);  // coalesced b64
    }
}

// ---------------------------------------------------------------------------
// Kernel 3: out[bc, h, w] = sum_p Bu[h,p] * T[bc,p,w]  — pure streaming.
// Grid (16 htiles, 128 bc) = 2048 blocks (2 rounds/CU). Thread t:
//   w0 = (t&127)*4, hq = t>>7 -> rows hq*16 .. +15 of the 32-row tile.
// T column slice in 16 NAMED float4 regs (L2-hit global dwordx4 loads).
// ---------------------------------------------------------------------------
__global__ __launch_bounds__(256, 4)
void bezier_eval(const float* __restrict__ T,
                 const float* __restrict__ Bu,
                 float* __restrict__ out) {
    __shared__ float Bu_s[HTILE * P16];   // 2 KiB

    const int t     = threadIdx.x;        // 0..255
    const int htile = blockIdx.x;         // 0..15
    const int bc    = blockIdx.y;         // 0..127

    *(float2*)&Bu_s[t * 2] = *(const float2*)&Bu[htile * (HTILE * P16) + t * 2];
    __syncthreads();

    const int w0 = (t & 127) * 4;
    const int hq = t >> 7;                // 0 or 1

    const float* Tp = T + (size_t)bc * (P16 * Ww) + w0;
    float4 T0  = *(const float4*)&Tp[ 0 * Ww];
    float4 T1  = *(const float4*)&Tp[ 1 * Ww];
    float4 T2  = *(const float4*)&Tp[ 2 * Ww];
    float4 T3  = *(const float4*)&Tp[ 3 * Ww];
    float4 T4  = *(const float4*)&Tp[ 4 * Ww];
    float4 T5  = *(const float4*)&Tp[ 5 * Ww];
    float4 T6  = *(const float4*)&Tp[ 6 * Ww];
    float4 T7  = *(const float4*)&Tp[ 7 * Ww];
    float4 T8  = *(const float4*)&Tp[ 8 * Ww];
    float4 T9  = *(const float4*)&Tp[ 9 * Ww];
    float4 T10 = *(const float4*)&Tp[10 * Ww];
    float4 T11 = *(const float4*)&Tp[11 * Ww];
    float4 T12 = *(const float4*)&Tp[12 * Ww];
    float4 T13 = *(const float4*)&Tp[13 * Ww];
    float4 T14 = *(const float4*)&Tp[14 * Ww];
    float4 T15 = *(const float4*)&Tp[15 * Ww];

    const size_t out_row0 =
        ((size_t)bc * Hh + (size_t)htile * HTILE + hq * 16) * Ww + w0;

    #pragma unroll
    for (int h = 0; h < 16; ++h) {
        const int hh = hq * 16 + h;
        const float4* burow = (const float4*)&Bu_s[hh * P16];  // uniform broadcast
        float4 b0 = burow[0], b1 = burow[1], b2 = burow[2], b3 = burow[3];
        float4 acc = make_float4(0.f, 0.f, 0.f, 0.f);
        #define FMA4(b, Tv) \
            acc.x = fmaf((b), (Tv).x, acc.x); \
            acc.y = fmaf((b), (Tv).y, acc.y); \
            acc.z = fmaf((b), (Tv).z, acc.z); \
            acc.w = fmaf((b), (Tv).w, acc.w);
        FMA4(b0.x, T0);  FMA4(b0.y, T1);  FMA4(b0.z, T2);  FMA4(b0.w, T3);
        FMA4(b1.x, T4);  FMA4(b1.y, T5);  FMA4(b1.z, T6);  FMA4(b1.w, T7);
        FMA4(b2.x, T8);  FMA4(b2.y, T9);  FMA4(b2.z, T10); FMA4(b2.w, T11);
        FMA4(b3.x, T12); FMA4(b3.y, T13); FMA4(b3.z, T14); FMA4(b3.w, T15);
        #undef FMA4
        f32x4 accv = { acc.x, acc.y, acc.z, acc.w };
        __builtin_nontemporal_store(accv, (f32x4*)&out[out_row0 + (size_t)h * Ww]);
    }
}

extern "C" void kernel_launch(void* const* d_in, const int* in_sizes, int n_in,
                              void* d_out, int out_size, void* d_ws, size_t ws_size,
                              hipStream_t stream) {
    const float* K     = (const float*)d_in[0];   // [128, 16, 16]
    const float* basis = (const float*)d_in[1];   // [262144, 16, 16]
    float* out = (float*)d_out;                   // [128, 512, 512]

    float* Bu = (float*)d_ws;                     // [512][16]   32 KiB
    float* Bv = Bu + Hh * P16;                    // [512][16]   32 KiB
    float* T  = Bv + Ww * Q16;                    // [128][16][512]  4 MiB

    extract_factors<<<4, 256, 0, stream>>>(basis, Bu, Bv);
    build_T<<<BC, 256, 0, stream>>>(K, Bv, T);

    dim3 grid(NHT, BC);
    bezier_eval<<<grid, 256, 0, stream>>>(T, Bu, out);
}